// Round 4
// baseline (295.839 us; speedup 1.0000x reference)
//
#include <hip/hip_runtime.h>

#define BLOCK 256
#define NB 5      // objects per scene
#define DD 12     // per-object feature dim
#define EE 64     // goal embedding dim
#define HH 32     // F1 hidden dim
#define ROW 81    // D + E + N
#define OUTW 405  // N * ROW

__global__ __launch_bounds__(BLOCK, 2) void fused_relnet_kernel(
    const float* __restrict__ obs, const float* __restrict__ ghat,
    const float* __restrict__ W1, const float* __restrict__ b1,
    const float* __restrict__ W2, const float* __restrict__ b2,
    float* __restrict__ out, int B)
{
    __shared__ float s_g2[BLOCK * 33];   // per-thread W2@ghat (stride 33: conflict-free)
    __shared__ float s_zhat[BLOCK * NB];
    __shared__ float s_w2s[HH];          // rowsum(W2)
    __shared__ float s_sb2;              // sum(b2)

    const int tid = threadIdx.x;
    const int r0 = blockIdx.x * BLOCK;
    const int i = r0 + tid;              // batch index
    const bool valid = (i < B);

    // ---- batch-independent scalars (one wave, once per block) ----
    if (tid < HH) {
        float s = 0.f;
        const float4* p = reinterpret_cast<const float4*>(W2 + tid * EE);
        #pragma unroll
        for (int q = 0; q < EE / 4; ++q) { float4 v = p[q]; s += v.x + v.y + v.z + v.w; }
        s_w2s[tid] = s;
    } else if (tid == HH) {
        float s = 0.f;
        #pragma unroll
        for (int e = 0; e < EE; ++e) s += b2[e];
        s_sb2 = s;
    }

    float o[NB * DD];
    if (valid) {
        // ---- obs row (60 floats) into registers, issued early ----
        {
            const float4* p = reinterpret_cast<const float4*>(obs + (size_t)i * (NB * DD));
            #pragma unroll
            for (int q = 0; q < NB * DD / 4; ++q) {
                float4 v = p[q];
                o[4*q+0] = v.x; o[4*q+1] = v.y; o[4*q+2] = v.z; o[4*q+3] = v.w;
            }
        }

        // ---- GEMV g2 = W2 @ ghat_i, accumulator-interleaved (dep distance 32) ----
        float g2[HH];
        #pragma unroll
        for (int h = 0; h < HH; ++h) g2[h] = 0.f;
        const float* grow = ghat + (size_t)i * EE;
        for (int ec = 0; ec < 4; ++ec) {          // runtime loop: 16 e per chunk
            float gc[16];
            const float4* gp = reinterpret_cast<const float4*>(grow + ec * 16);
            #pragma unroll
            for (int q = 0; q < 4; ++q) {
                float4 v = gp[q];
                gc[4*q+0] = v.x; gc[4*q+1] = v.y; gc[4*q+2] = v.z; gc[4*q+3] = v.w;
            }
            #pragma unroll
            for (int q = 0; q < 16; ++q) {        // q outer, h inner: independent accs
                #pragma unroll
                for (int h = 0; h < HH; ++h)
                    g2[h] += gc[q] * W2[h * EE + ec * 16 + q];   // W2: wave-uniform s_loads
            }
        }
        #pragma unroll
        for (int h = 0; h < HH; ++h) s_g2[tid * 33 + h] = g2[h];
    }
    __syncthreads();   // publishes s_g2 / s_w2s / s_sb2

    if (valid) {
        float w[NB * NB];    // logits (b2.ghat term softmax-invariant: dropped)
        float hw[NB * NB];   // h . rowsum(W2)
        #pragma unroll
        for (int q = 0; q < NB * NB; ++q) { w[q] = 0.f; hw[q] = 0.f; }

        for (int c = 0; c < HH / 8; ++c) {        // runtime chunk loop (rule #20 safe)
            float g2c[8], w2c[8];
            #pragma unroll
            for (int hp = 0; hp < 8; ++hp) {
                g2c[hp] = s_g2[tid * 33 + c * 8 + hp];
                w2c[hp] = s_w2s[c * 8 + hp];
            }
            #pragma unroll
            for (int hp = 0; hp < 8; ++hp) {
                const int h = c * 8 + hp;          // wave-uniform -> scalar W1/b1 loads
                float a[NB], bb[NB];
                #pragma unroll
                for (int j = 0; j < NB; ++j) { a[j] = b1[h]; bb[j] = 0.f; }
                #pragma unroll
                for (int d = 0; d < DD; ++d) {     // d outer, j inner: dep distance 10
                    const float w1t = W1[d * HH + h];
                    const float w1b = W1[(DD + d) * HH + h];
                    #pragma unroll
                    for (int j = 0; j < NB; ++j) {
                        a[j]  += o[j*DD + d] * w1t;
                        bb[j] += o[j*DD + d] * w1b;
                    }
                }
                #pragma unroll
                for (int j = 0; j < NB; ++j) {
                    #pragma unroll
                    for (int k = 0; k < NB; ++k) {
                        float hv = fmaxf(a[j] + bb[k], 0.f);
                        w[j*NB + k]  += hv * g2c[hp];
                        hw[j*NB + k] += hv * w2c[hp];
                    }
                }
            }
        }

        // ---- softmax over 25 pairs: tree max (depth 5), then exp/accumulate ----
        float mx[32];
        #pragma unroll
        for (int q = 0; q < 25; ++q) mx[q] = w[q];
        #pragma unroll
        for (int q = 25; q < 32; ++q) mx[q] = w[0];
        #pragma unroll
        for (int s = 16; s >= 1; s >>= 1) {
            #pragma unroll
            for (int q = 0; q < s; ++q) mx[q] = fmaxf(mx[q], mx[q + s]);
        }
        const float m = mx[0];

        float zacc[NB], racc[NB];
        #pragma unroll
        for (int j = 0; j < NB; ++j) { zacc[j] = 0.f; racc[j] = 0.f; }
        #pragma unroll
        for (int j = 0; j < NB; ++j) {
            #pragma unroll
            for (int k = 0; k < NB; ++k) {
                float e = __expf(w[j*NB + k] - m);
                zacc[j] += e * hw[j*NB + k];
                racc[j] += e;
            }
        }
        const float l = ((racc[0] + racc[1]) + (racc[2] + racc[3])) + racc[4];
        const float invl = 1.f / l;
        const float sb2 = s_sb2;
        #pragma unroll
        for (int j = 0; j < NB; ++j)
            s_zhat[tid * NB + j] = (zacc[j] + sb2 * racc[j]) * invl;
    }
    __syncthreads();

    // ---- write phase: dense ascending coalesced stores (nontemporal) ----
    const int rows = (B - r0 < BLOCK) ? (B - r0) : BLOCK;
    const size_t obase = (size_t)r0 * OUTW;
    for (int t = tid; t < rows * OUTW; t += BLOCK) {
        const int il = t / OUTW;            // magic-mul div
        const int r  = t - il * OUTW;
        const int j  = r / ROW;
        const int rr = r - j * ROW;
        const int ib = r0 + il;
        float v;
        if (rr < DD)           v = obs[(size_t)ib * (NB * DD) + j * DD + rr];   // L2-hot
        else if (rr < DD + EE) v = ghat[(size_t)ib * EE + (rr - DD)];           // L2-hot
        else                   v = s_zhat[il * NB + (rr - (DD + EE))];
        __builtin_nontemporal_store(v, &out[obase + t]);
    }
}

extern "C" void kernel_launch(void* const* d_in, const int* in_sizes, int n_in,
                              void* d_out, int out_size, void* d_ws, size_t ws_size,
                              hipStream_t stream) {
    const float* obs  = (const float*)d_in[0];
    const float* ghat = (const float*)d_in[1];
    const float* W1   = (const float*)d_in[2];
    const float* b1   = (const float*)d_in[3];
    const float* W2   = (const float*)d_in[4];
    const float* b2   = (const float*)d_in[5];
    float* out = (float*)d_out;

    const int B = in_sizes[0] / (NB * DD);
    const int grid = (B + BLOCK - 1) / BLOCK;
    hipLaunchKernelGGL(fused_relnet_kernel, dim3(grid), dim3(BLOCK), 0, stream,
                       obs, ghat, W1, b1, W2, b2, out, B);
}

// Round 5
// 180.912 us; speedup vs baseline: 1.6353x; 1.6353x over previous
//
#include <hip/hip_runtime.h>

#define BLOCK 256
#define NB 5      // objects per scene
#define DD 12     // per-object feature dim
#define EE 64     // goal embedding dim
#define HH 32     // F1 hidden dim
#define ROW 81    // D + E + N
#define OUTW 405  // N * ROW
#define SUB 64    // rows per write sub-tile

__global__ __launch_bounds__(BLOCK, 2) void fused_relnet_kernel(
    const float* __restrict__ obs, const float* __restrict__ ghat,
    const float* __restrict__ W1, const float* __restrict__ b1,
    const float* __restrict__ W2, const float* __restrict__ b2,
    float* __restrict__ out, int B)
{
    // s_buf: compute phase = per-thread g2 (tid*33+h, conflict-free);
    //        write phase   = staging [SUB*60 obs | SUB*64 ghat] (7936 floats)
    __shared__ float s_buf[BLOCK * 33];
    __shared__ float s_zhat[BLOCK * NB];
    __shared__ float s_w2s[HH];          // rowsum(W2)
    __shared__ float s_sb2;              // sum(b2)

    const int tid = threadIdx.x;
    const int r0 = blockIdx.x * BLOCK;
    const int i = r0 + tid;              // batch index
    const bool valid = (i < B);

    // ---- batch-independent scalars ----
    if (tid < HH) {
        float s = 0.f;
        const float4* p = reinterpret_cast<const float4*>(W2 + tid * EE);
        #pragma unroll
        for (int q = 0; q < EE / 4; ++q) { float4 v = p[q]; s += v.x + v.y + v.z + v.w; }
        s_w2s[tid] = s;
    } else if (tid == HH) {
        float s = 0.f;
        #pragma unroll
        for (int e = 0; e < EE; ++e) s += b2[e];
        s_sb2 = s;
    }

    float o[NB * DD];
    if (valid) {
        // ---- obs row (60 floats) into registers ----
        {
            const float4* p = reinterpret_cast<const float4*>(obs + (size_t)i * (NB * DD));
            #pragma unroll
            for (int q = 0; q < NB * DD / 4; ++q) {
                float4 v = p[q];
                o[4*q+0] = v.x; o[4*q+1] = v.y; o[4*q+2] = v.z; o[4*q+3] = v.w;
            }
        }
        // ---- GEMV g2 = W2 @ ghat_i, accumulator-interleaved (32 indep accs) ----
        float g2[HH];
        #pragma unroll
        for (int h = 0; h < HH; ++h) g2[h] = 0.f;
        const float* grow = ghat + (size_t)i * EE;
        for (int ec = 0; ec < 4; ++ec) {
            float gc[16];
            const float4* gp = reinterpret_cast<const float4*>(grow + ec * 16);
            #pragma unroll
            for (int q = 0; q < 4; ++q) {
                float4 v = gp[q];
                gc[4*q+0] = v.x; gc[4*q+1] = v.y; gc[4*q+2] = v.z; gc[4*q+3] = v.w;
            }
            #pragma unroll
            for (int q = 0; q < 16; ++q) {
                #pragma unroll
                for (int h = 0; h < HH; ++h)
                    g2[h] += gc[q] * W2[h * EE + ec * 16 + q];  // wave-uniform -> s_load
            }
        }
        #pragma unroll
        for (int h = 0; h < HH; ++h) s_buf[tid * 33 + h] = g2[h];
    }
    __syncthreads();   // publishes s_buf(g2) / s_w2s / s_sb2

    if (valid) {
        float w[NB * NB];    // logits (b2.ghat term softmax-invariant: dropped)
        float hw[NB * NB];   // h . rowsum(W2)
        #pragma unroll
        for (int q = 0; q < NB * NB; ++q) { w[q] = 0.f; hw[q] = 0.f; }

        for (int c = 0; c < HH / 8; ++c) {        // runtime chunk loop
            float g2c[8], w2c[8];
            #pragma unroll
            for (int hp = 0; hp < 8; ++hp) {
                g2c[hp] = s_buf[tid * 33 + c * 8 + hp];
                w2c[hp] = s_w2s[c * 8 + hp];
            }
            #pragma unroll
            for (int hp = 0; hp < 8; ++hp) {
                const int h = c * 8 + hp;          // wave-uniform -> scalar W1/b1 loads
                float a[NB], bb[NB];
                #pragma unroll
                for (int j = 0; j < NB; ++j) { a[j] = b1[h]; bb[j] = 0.f; }
                #pragma unroll
                for (int d = 0; d < DD; ++d) {     // d outer, j inner: 10 indep accs
                    const float w1t = W1[d * HH + h];
                    const float w1b = W1[(DD + d) * HH + h];
                    #pragma unroll
                    for (int j = 0; j < NB; ++j) {
                        a[j]  += o[j*DD + d] * w1t;
                        bb[j] += o[j*DD + d] * w1b;
                    }
                }
                #pragma unroll
                for (int j = 0; j < NB; ++j) {
                    #pragma unroll
                    for (int k = 0; k < NB; ++k) {
                        float hv = fmaxf(a[j] + bb[k], 0.f);
                        w[j*NB + k]  += hv * g2c[hp];
                        hw[j*NB + k] += hv * w2c[hp];
                    }
                }
            }
        }

        // ---- softmax over 25 pairs: tree max, then exp/accumulate ----
        float mx[32];
        #pragma unroll
        for (int q = 0; q < 25; ++q) mx[q] = w[q];
        #pragma unroll
        for (int q = 25; q < 32; ++q) mx[q] = w[0];
        #pragma unroll
        for (int s = 16; s >= 1; s >>= 1) {
            #pragma unroll
            for (int q = 0; q < s; ++q) mx[q] = fmaxf(mx[q], mx[q + s]);
        }
        const float m = mx[0];

        float zacc[NB], racc[NB];
        #pragma unroll
        for (int j = 0; j < NB; ++j) { zacc[j] = 0.f; racc[j] = 0.f; }
        #pragma unroll
        for (int j = 0; j < NB; ++j) {
            #pragma unroll
            for (int k = 0; k < NB; ++k) {
                float e = __expf(w[j*NB + k] - m);
                zacc[j] += e * hw[j*NB + k];
                racc[j] += e;
            }
        }
        const float l = ((racc[0] + racc[1]) + (racc[2] + racc[3])) + racc[4];
        const float invl = 1.f / l;
        const float sb2 = s_sb2;
        #pragma unroll
        for (int j = 0; j < NB; ++j)
            s_zhat[tid * NB + j] = (zacc[j] + sb2 * racc[j]) * invl;
    }
    __syncthreads();   // compute done; s_buf free for reuse

    // ---- write phase: 4 sub-tiles of 64 rows, LDS-staged, dense stores ----
    float* s_obs = s_buf;                 // SUB*60 = 3840 floats
    float* s_gh  = s_buf + SUB * NB * DD; // SUB*64 = 4096 floats
    const int rows_blk = (B - r0 < BLOCK) ? (B - r0) : BLOCK;

    for (int sblk = 0; sblk < BLOCK / SUB; ++sblk) {
        const int rs0 = sblk * SUB;                       // row offset within block
        if (rs0 >= rows_blk) break;
        const int rows = (rows_blk - rs0 < SUB) ? (rows_blk - rs0) : SUB;
        const int gr0 = r0 + rs0;                         // global row

        // coalesced staging (independent loads -> pipelined)
        for (int t = tid; t < rows * NB * DD; t += BLOCK)
            s_obs[t] = obs[(size_t)gr0 * (NB * DD) + t];
        for (int t = tid; t < rows * EE; t += BLOCK)
            s_gh[t] = ghat[(size_t)gr0 * EE + t];
        __syncthreads();

        // dense ascending coalesced stores
        const size_t obase = (size_t)gr0 * OUTW;
        for (int t = tid; t < rows * OUTW; t += BLOCK) {
            const int il = t / OUTW;
            const int r  = t - il * OUTW;
            const int j  = r / ROW;
            const int rr = r - j * ROW;
            float v;
            if (rr < DD)           v = s_obs[il * NB * DD + j * DD + rr];
            else if (rr < DD + EE) v = s_gh[il * EE + (rr - DD)];
            else                   v = s_zhat[(rs0 + il) * NB + (rr - (DD + EE))];
            out[obase + t] = v;
        }
        __syncthreads();   // before next sub-tile overwrites staging
    }
}

extern "C" void kernel_launch(void* const* d_in, const int* in_sizes, int n_in,
                              void* d_out, int out_size, void* d_ws, size_t ws_size,
                              hipStream_t stream) {
    const float* obs  = (const float*)d_in[0];
    const float* ghat = (const float*)d_in[1];
    const float* W1   = (const float*)d_in[2];
    const float* b1   = (const float*)d_in[3];
    const float* W2   = (const float*)d_in[4];
    const float* b2   = (const float*)d_in[5];
    float* out = (float*)d_out;

    const int B = in_sizes[0] / (NB * DD);
    const int grid = (B + BLOCK - 1) / BLOCK;
    hipLaunchKernelGGL(fused_relnet_kernel, dim3(grid), dim3(BLOCK), 0, stream,
                       obs, ghat, W1, b1, W2, b2, out, B);
}